// Round 7
// baseline (283.653 us; speedup 1.0000x reference)
//
#include <hip/hip_runtime.h>
#include <hip/hip_bf16.h>

#define NH 16
#define HS 64
#define CE 1024
#define BB 4
#define TT 2048

typedef __bf16 bf16;
typedef __bf16 v8bf __attribute__((ext_vector_type(8)));
typedef __bf16 v4bf __attribute__((ext_vector_type(4)));
typedef __bf16 v2bf __attribute__((ext_vector_type(2)));
typedef float v4f __attribute__((ext_vector_type(4)));
typedef float v16f __attribute__((ext_vector_type(16)));

#define GLD16(gp, lp)                                                              \
    __builtin_amdgcn_global_load_lds((const __attribute__((address_space(1))) void*)(gp), \
                                     (__attribute__((address_space(3))) void*)(lp), 16, 0, 0)

// raw-barrier discipline: sched_barrier(0) fences pin ordering around inline waits
#define FENCE() __builtin_amdgcn_sched_barrier(0)
#define BARRIER() { FENCE(); __builtin_amdgcn_s_barrier(); FENCE(); }
#define VM2()  { asm volatile("s_waitcnt vmcnt(2)" ::: "memory"); FENCE(); }
#define VM8()  { asm volatile("s_waitcnt vmcnt(8)" ::: "memory"); FENCE(); }
#define VM0()  { asm volatile("s_waitcnt vmcnt(0)" ::: "memory"); FENCE(); }

// ---------------- fused prep: cast x, cos/sin tables, 4 weight transposes ----------------
// bid [0,4096): cast x fp32->bf16 ; [4096,4352): cs tables ; [4352,5376): weight transpose
__global__ __launch_bounds__(256) void prep_kernel(const float* __restrict__ x,
                                                   const float* __restrict__ W0,
                                                   const float* __restrict__ W1,
                                                   const float* __restrict__ W2,
                                                   const float* __restrict__ W3,
                                                   bf16* __restrict__ xb,
                                                   float2* __restrict__ csQ,
                                                   float2* __restrict__ csK,
                                                   bf16* __restrict__ dqkv,
                                                   bf16* __restrict__ dp) {
    __shared__ bf16 tile[64][66];
    const int bid = blockIdx.x;
    const int tid = threadIdx.x;
    if (bid < 4096) {
        int idx = (bid * 256 + tid) * 8;
        const float4* xp = (const float4*)(x + idx);
        float4 a = xp[0], b = xp[1];
        v8bf o;
        o[0] = (bf16)a.x; o[1] = (bf16)a.y; o[2] = (bf16)a.z; o[3] = (bf16)a.w;
        o[4] = (bf16)b.x; o[5] = (bf16)b.y; o[6] = (bf16)b.z; o[7] = (bf16)b.w;
        *(v8bf*)(xb + idx) = o;
    } else if (bid < 4352) {
        int idx = (bid - 4096) * 256 + tid;  // 65536 = 2048 t x 32 i
        int t = idx >> 5, i = idx & 31;
        float inv = exp2f(-0.41524101186092034f * (float)i);  // 10000^(-i/32)
        float ang = (float)t * inv;
        float s, c;
        sincosf(ang, &s, &c);
        const float QS = 0.18033688011112042f;  // 0.125 * log2(e): softmax runs base-2
        csK[idx] = make_float2(c, s);
        csQ[idx] = make_float2(c * QS, s * QS);
    } else {
        int idx = bid - 4352;
        int z = idx >> 8, rem = idx & 255;
        const float* W = (z == 0) ? W0 : (z == 1) ? W1 : (z == 2) ? W2 : W3;
        bf16* Wt = (z < 3) ? (dqkv + (size_t)z * 1024 * CE) : dp;
        int k0 = (rem & 15) * 64;
        int n0 = (rem >> 4) * 64;
        int tx = tid & 63;
        int ty = tid >> 6;  // 0..3
        for (int s = 0; s < 16; s++) {
            int r = s * 4 + ty;
            tile[r][tx] = (bf16)W[(size_t)(k0 + r) * CE + n0 + tx];
        }
        __syncthreads();
        for (int s = 0; s < 16; s++) {
            int r = s * 4 + ty;
            Wt[(size_t)(n0 + r) * CE + k0 + tx] = tile[tx][r];
        }
    }
}

// ---------------- shared GEMM macros: BK=64, XOR-swizzled LDS, dbuf prefetch ------------
// STRUCTURAL CEILING (r2/r3): 2-phase 128^2 at K=1024 lands ~680 TF; 8-phase 256^2 is
// grid-quantization-blocked. Schedule frozen. r5: + bijective XCD m-chunk swizzle with
// serpentine n-order (T1): each XCD owns total/8 consecutive blocks = 8 m-panels (A chunk
// 2MB L2-resident, read from HBM once); B panels cycle with zig-zag to cut LRU thrash.
#define GSTAGE(AD, BD, kk) {                                                        \
    _Pragma("unroll") for (int p = 0; p < 4; p++)                                   \
        GLD16(Ag + (kk) + (size_t)(p * 32) * CE, (AD) + p * 2048);                  \
    _Pragma("unroll") for (int p = 0; p < 4; p++)                                   \
        GLD16(Bg + (kk) + (size_t)(p * 32) * CE, (BD) + p * 2048); }

#define GCOMPUTE(ASrc, BSrc)                                                        \
    _Pragma("unroll")                                                               \
    for (int kh = 0; kh < 2; kh++) {                                                \
        v8bf af[4], bfr[4];                                                         \
        for (int i = 0; i < 4; i++) {                                               \
            int row = wr * 64 + i * 16 + lane15;                                    \
            af[i] = *(const v8bf*)(&ASrc[row * 64 + (((kh * 4 + quad) ^ (lane15 & 7)) * 8)]); \
        }                                                                           \
        for (int j = 0; j < 4; j++) {                                               \
            int row = wc * 64 + j * 16 + lane15;                                    \
            bfr[j] = *(const v8bf*)(&BSrc[row * 64 + (((kh * 4 + quad) ^ (lane15 & 7)) * 8)]); \
        }                                                                           \
        for (int i = 0; i < 4; i++)                                                 \
            for (int j = 0; j < 4; j++)                                             \
                acc[i][j] = __builtin_amdgcn_mfma_f32_16x16x32_bf16(af[i], bfr[j], acc[i][j], 0, 0, 0); \
    }

#define GEMM_PROLOG(Abuf, Bbuf)                                                     \
    __shared__ __align__(16) bf16 As0[128 * 64];                                    \
    __shared__ __align__(16) bf16 Bs0[128 * 64];                                    \
    __shared__ __align__(16) bf16 As1[128 * 64];                                    \
    __shared__ __align__(16) bf16 Bs1[128 * 64];                                    \
    const int tid = threadIdx.x;                                                    \
    const int lane = tid & 63, wave = tid >> 6;                                     \
    const int lane15 = lane & 15, quad = lane >> 4;                                 \
    const int wr = wave >> 1, wc = wave & 1;                                        \
    const int fid = blockIdx.y * gridDim.x + blockIdx.x;                            \
    const int bchunk = (gridDim.x * gridDim.y) >> 3;                                \
    const int swzb = (fid & 7) * bchunk + (fid >> 3);                               \
    const int bmy = swzb / gridDim.x;                                               \
    const int bnx0 = swzb % gridDim.x;                                              \
    const int bnx = (bmy & 1) ? (gridDim.x - 1 - bnx0) : bnx0;                      \
    const int m0 = bmy * 128;                                                       \
    const int n0 = bnx * 128;                                                       \
    v4f acc[4][4] = {};                                                             \
    const int cm = tid >> 3;                                                        \
    const int ck = ((tid & 7) ^ (cm & 7)) * 8;                                      \
    const bf16* Ag = (Abuf) + (size_t)(m0 + cm) * CE + ck;                          \
    const bf16* Bg = (Bbuf) + (size_t)(n0 + cm) * CE + ck;                          \
    bf16* aD0 = &As0[wave * 512];                                                   \
    bf16* bD0 = &Bs0[wave * 512];                                                   \
    bf16* aD1 = &As1[wave * 512];                                                   \
    bf16* bD1 = &Bs1[wave * 512];

#define GEMM_KLOOP()                                                                \
    GSTAGE(aD0, bD0, 0);                                                            \
    for (int k0 = 0; k0 < CE; k0 += 128) {                                          \
        GSTAGE(aD1, bD1, k0 + 64);                                                  \
        VM8(); BARRIER();                                                           \
        GCOMPUTE(As0, Bs0);                                                         \
        BARRIER();                                                                  \
        GSTAGE(aD0, bD0, (k0 + 128) & 1023);                                        \
        VM8(); BARRIER();                                                           \
        GCOMPUTE(As1, Bs1);                                                         \
        BARRIER();                                                                  \
    }                                                                               \
    VM0();

// ---------------- QKV GEMM: C(8192 x 3072) = Xb * WqkvT^T, RoPE/V-transpose fused -------
__global__ __launch_bounds__(256) void gemm_qkv(const bf16* __restrict__ A,
                                                const bf16* __restrict__ Bt,
                                                bf16* __restrict__ Qb_, bf16* __restrict__ Kb_,
                                                bf16* __restrict__ Vt_,
                                                const float2* __restrict__ csQ,
                                                const float2* __restrict__ csK) {
    GEMM_PROLOG(A, Bt)
    GEMM_KLOOP()

    for (int i = 0; i < 4; i++) {
        for (int j = 0; j < 4; j++) {
            int gmb = m0 + wr * 64 + i * 16 + quad * 4;
            int gn = n0 + wc * 64 + j * 16 + lane15;
            int w = gn >> 10;           // 0=Q 1=K 2=V (block-uniform)
            int n = gn & 1023;
            int hh = n >> 6, d = n & 63;
            if (w < 2) {
                // fused RoPE, parity-row split: lane pair (d,d+1) exchanges raw acc via
                // shfl_xor(1); each lane produces BOTH rotated outputs of the pair for
                // 2 of the 4 rows (even lanes r=0,1; odd lanes r=2,3) -> 2 float2
                // cs-loads + 2 v2bf stores per tile instead of 4+4.
                bf16* out = w ? Kb_ : Qb_;
                const float2* csRow = (w ? csK : csQ) + (d >> 1);
                const int par = gn & 1;
                const int dbase = d & ~1;
                const int b = gmb >> 11, tbase = gmb & 2047;  // 4-row group never crosses b
                const float xv0 = acc[i][j][0], xv1 = acc[i][j][1];
                const float xv2 = acc[i][j][2], xv3 = acc[i][j][3];
                const float pv0 = __shfl_xor(xv0, 1), pv1 = __shfl_xor(xv1, 1);
                const float pv2 = __shfl_xor(xv2, 1), pv3 = __shfl_xor(xv3, 1);
                const float xa = par ? xv2 : xv0, pa = par ? pv2 : pv0;
                const float xb2 = par ? xv3 : xv1, pb = par ? pv3 : pv1;
                const float ua = par ? pa : xa, va = par ? xa : pa;   // (even-d, odd-d)
                const float ub = par ? pb : xb2, vb = par ? xb2 : pb;
                const int ta = tbase + (par << 1), tb = ta + 1;
                const float2 csa = csRow[ta * 32];
                const float2 csb = csRow[tb * 32];
                v2bf sa, sb;
                sa[0] = (bf16)(ua * csa.x - va * csa.y);
                sa[1] = (bf16)(ua * csa.y + va * csa.x);
                sb[0] = (bf16)(ub * csb.x - vb * csb.y);
                sb[1] = (bf16)(ub * csb.y + vb * csb.x);
                bf16* rowp = out + ((size_t)(b * NH + hh)) * TT * HS + dbase;
                *(v2bf*)(rowp + (size_t)ta * HS) = sa;
                *(v2bf*)(rowp + (size_t)tb * HS) = sb;
            } else {  // V transposed: Vt [B][H][HS][T]
                int b = gmb >> 11, t = gmb & 2047;
                v4bf pack;
                for (int r = 0; r < 4; r++) pack[r] = (bf16)acc[i][j][r];
                *(v4bf*)(&Vt_[(((size_t)(b * NH + hh)) * HS + d) * TT + t]) = pack;
            }
        }
    }
}

// ---------------- projection GEMM: out(8192 x 1024) = Ob * WpT^T + bias, fp32 ----------
__global__ __launch_bounds__(256) void gemm_proj(const bf16* __restrict__ A,
                                                 const bf16* __restrict__ Bt,
                                                 float* __restrict__ Pout,
                                                 const float* __restrict__ bias) {
    GEMM_PROLOG(A, Bt)

    // bias prefetch: acc-independent, issued before the K-loop so the epilogue's
    // stores don't sit on a fresh scattered-load latency chain after the VM0 drain.
    float bb[4];
#pragma unroll
    for (int j = 0; j < 4; j++) bb[j] = bias[n0 + wc * 64 + j * 16 + lane15];

    GEMM_KLOOP()

    for (int i = 0; i < 4; i++) {
        for (int j = 0; j < 4; j++) {
            int gmb = m0 + wr * 64 + i * 16 + quad * 4;
            int gn = n0 + wc * 64 + j * 16 + lane15;
            for (int r = 0; r < 4; r++)
                Pout[(size_t)(gmb + r) * CE + gn] = acc[i][j][r] + bb[j];
        }
    }
}

// ---------------- flash attention v10: 8 waves/block, 32 q-rows/wave -------------------
// Same per-wave math as proven v8; block q-span doubles to 256, so each staged K/V tile
// serves 2x the FLOPs: staging calls and barrier-pairs per q-row HALVE. TLP preserved
// (r4 lesson): 2 blocks/CU x 8 waves = 16 waves/CU, identical to v8's 4 blocks x 4.
// 512 threads cover an 8KB tile in ONE global_load_lds -> 2 calls/tile, vmcnt(2).
// Grid 512 = exactly one full round. Block map: bh = (bid&7) + 8*((bid>>3)>>3) keeps
// 8 heads (4MB KV) per XCD-L2; qb = bal((bid>>3)&7) with bal = {7,0,6,1,5,2,4,3} makes
// any two consecutive same-XCD blocks (one CU's pair) sum to 36 tiles: perfect balance.
// Causal: per-wave predication (kvs <= q0), waves idle-at-barrier past their diag.
#define ASTAGE(KD, VD, kv) {                                        \
    GLD16(kg + (size_t)(kv) * HS, (KD));                            \
    GLD16(vg + (kv), (VD)); }

#define ACOMPUTE(KS, VS, KVB)                                                       \
    _Pragma("unroll")                                                               \
    for (int sub = 0; sub < 2; sub++) {                                             \
        const int kvs = (KVB) + sub * 32;                                           \
        if (kvs > q0) break;                                                        \
        const bool diag = (kvs == q0);                                              \
        v16f s = {};                                                                \
        __builtin_amdgcn_s_setprio(1);                                              \
        for (int m = 0; m < 4; m++) {                                               \
            v8bf afr = *(const v8bf*)(&KS[(sub * 32 + lane31) * 64 +                \
                                          (((m << 1) | h) ^ (lane31 & 7)) * 8]);    \
            s = __builtin_amdgcn_mfma_f32_32x32x16_bf16(afr, qf[m], s, 0, 0, 0);    \
        }                                                                           \
        __builtin_amdgcn_s_setprio(0);                                              \
        float p[16];                                                                \
        if (diag) {                                                                 \
            for (int r = 0; r < 16; r++) {                                          \
                int kvr = (r & 3) + 8 * (r >> 2) + 4 * h;                           \
                p[r] = exp2f((kvr <= lane31) ? s[r] : -3.0e38f);                    \
            }                                                                       \
        } else {                                                                    \
            for (int r = 0; r < 16; r++) p[r] = exp2f(s[r]);                        \
        }                                                                           \
        float a8[8];                                                                \
        for (int r = 0; r < 8; r++) a8[r] = p[r] + p[r + 8];                        \
        l_i += ((a8[0] + a8[1]) + (a8[2] + a8[3])) + ((a8[4] + a8[5]) + (a8[6] + a8[7])); \
        union { v4bf v; unsigned long long u; } ch[4];                              \
        for (int g = 0; g < 4; g++)                                                 \
            for (int rr = 0; rr < 4; rr++)                                          \
                ch[g].v[rr] = (bf16)p[g * 4 + rr];                                  \
        __builtin_amdgcn_s_setprio(1);                                              \
        for (int t2 = 0; t2 < 2; t2++) {                                            \
            unsigned long long mine0 = ch[2 * t2].u, mine1 = ch[2 * t2 + 1].u;      \
            unsigned long long send = h ? mine0 : mine1;                            \
            unsigned long long recv = __shfl_xor(send, 32);                         \
            union { v8bf v; unsigned long long u[2]; } bfr2;                        \
            bfr2.u[0] = h ? recv : mine0;                                           \
            bfr2.u[1] = h ? mine1 : recv;                                           \
            int cidx = (((sub << 2) + (t2 << 1) + h) ^ (lane31 & 7)) * 8;           \
            v8bf va0 = *(const v8bf*)(&VS[lane31 * 64 + cidx]);                     \
            o0 = __builtin_amdgcn_mfma_f32_32x32x16_bf16(va0, bfr2.v, o0, 0, 0, 0); \
            v8bf va1 = *(const v8bf*)(&VS[(32 + lane31) * 64 + cidx]);              \
            o1 = __builtin_amdgcn_mfma_f32_32x32x16_bf16(va1, bfr2.v, o1, 0, 0, 0); \
        }                                                                           \
        __builtin_amdgcn_s_setprio(0);                                              \
    }

__global__ __launch_bounds__(512, 4) void attn_kernel(const bf16* __restrict__ Qb,
                                                      const bf16* __restrict__ Kb,
                                                      const bf16* __restrict__ Vt,
                                                      bf16* __restrict__ Ob) {
    __shared__ __align__(16) bf16 Ks0[64 * 64];  // [kv][d], chunk-swizzled
    __shared__ __align__(16) bf16 Vs0[64 * 64];  // [d][kv], chunk-swizzled
    __shared__ __align__(16) bf16 Ks1[64 * 64];
    __shared__ __align__(16) bf16 Vs1[64 * 64];
    const int tid = threadIdx.x, lane = tid & 63, wave = tid >> 6;  // wave 0..7
    const int lane31 = lane & 31, h = lane >> 5;
    const int bid = blockIdx.x;
    const int x8 = bid & 7, jj = bid >> 3;
    const int bh = x8 + 8 * (jj >> 3);              // 8 heads per XCD (4MB KV in L2)
    const int s9 = jj & 7;
    const int qb = (s9 & 1) ? (s9 >> 1) : (7 - (s9 >> 1));  // heavy/light interleave
    const int q0 = qb * 256 + wave * 32;
    const bf16* Qp = Qb + (size_t)bh * TT * HS;
    const bf16* Kp = Kb + (size_t)bh * TT * HS;
    const bf16* Vp = Vt + (size_t)bh * HS * TT;

    // Q B-fragments: B[n=q=lane31][k=d in 16m+8h+j]
    v8bf qf[4];
    for (int m = 0; m < 4; m++)
        qf[m] = *(const v8bf*)(Qp + (size_t)(q0 + lane31) * HS + m * 16 + h * 8);

    v16f o0 = {}, o1 = {};   // O^T rows d=0..31 / 32..63, col q=lane31 (unnormalized)
    float l_i = 0.f;         // per-lane half-row sum; cross-lane combine at end

    // staging source (XOR-swizzled chunk); 512 threads cover a full 64x64 tile:
    // thread t -> row t>>3 (0..63), chunk t&7; dest linear t*16B (8 wave-uniform bases)
    const int kr = tid >> 3, kc = tid & 7;
    const bf16* kg = Kp + kr * HS + ((kc ^ (kr & 7)) * 8);
    const bf16* vg = Vp + (size_t)kr * TT + ((kc ^ (kr & 7)) * 8);
    bf16* ksD0 = &Ks0[wave * 512];
    bf16* vsD0 = &Vs0[wave * 512];
    bf16* ksD1 = &Ks1[wave * 512];
    bf16* vsD1 = &Vs1[wave * 512];

    const int kv_end = (qb + 1) * 256;  // tiles per block = 4qb+4 (even) -> exact 2/iter
    ASTAGE(ksD0, vsD0, 0);
    for (int kv0 = 0; kv0 < kv_end; kv0 += 128) {
        ASTAGE(ksD1, vsD1, kv0 + 64);              // prefetch tile t+1 (rows <= 2047)
        VM2(); BARRIER();                          // tile t landed (2 newer in flight)
        ACOMPUTE(Ks0, Vs0, kv0);
        BARRIER();                                 // all readers of buf0 done
        ASTAGE(ksD0, vsD0, (kv0 + 128) & 2047);    // prefetch t+2 (wraps to dummy at end)
        VM2(); BARRIER();                          // tile t+1 landed
        ACOMPUTE(Ks1, Vs1, kv0 + 64);
        BARRIER();
    }
    VM0();  // drain dangling dummy prefetches

    const int b = bh >> 4, hh = bh & 15;
    const int q = q0 + lane31;
    float lt = l_i + __shfl_xor(l_i, 32);  // combine the two half-row sums once
    float invl = 1.f / lt;
    bf16* outRow = Ob + ((size_t)(b * TT + q)) * CE + hh * HS;
    for (int g = 0; g < 4; g++) {
        v4bf w0, w1;
        for (int rr = 0; rr < 4; rr++) {
            w0[rr] = (bf16)(o0[g * 4 + rr] * invl);
            w1[rr] = (bf16)(o1[g * 4 + rr] * invl);
        }
        *(v4bf*)(outRow + g * 8 + h * 4) = w0;
        *(v4bf*)(outRow + 32 + g * 8 + h * 4) = w1;
    }
}

extern "C" void kernel_launch(void* const* d_in, const int* in_sizes, int n_in,
                              void* d_out, int out_size, void* d_ws, size_t ws_size,
                              hipStream_t stream) {
    const float* x  = (const float*)d_in[0];
    const float* Wq = (const float*)d_in[1];
    const float* Wk = (const float*)d_in[2];
    const float* Wv = (const float*)d_in[3];
    const float* Wp = (const float*)d_in[4];
    const float* bp = (const float*)d_in[5];
    char* ws = (char*)d_ws;
    const size_t MB = 1024 * 1024;
    bf16* Xb    = (bf16*)(ws);                // 16MB
    bf16* WqkvT = (bf16*)(ws + 16 * MB);      // 6MB: 3072 x 1024 (Q,K,V stacked)
    bf16* WpT   = (bf16*)(ws + 22 * MB);      // 2MB
    bf16* Qb    = (bf16*)(ws + 24 * MB);      // 16MB
    bf16* Kb    = (bf16*)(ws + 40 * MB);      // 16MB
    bf16* Vt    = (bf16*)(ws + 56 * MB);      // 16MB
    bf16* Ob    = (bf16*)(ws + 72 * MB);      // 16MB (attn output)
    // cs tables live in the Ob region: consumed by the QKV GEMM, which completes
    // before attn writes Ob (single stream). 1MB total.
    float2* csQ = (float2*)(ws + 72 * MB);
    float2* csK = (float2*)(ws + 72 * MB + 512 * 1024);

    prep_kernel<<<dim3(5376), dim3(256), 0, stream>>>(x, Wq, Wk, Wv, Wp, Xb, csQ, csK,
                                                      WqkvT, WpT);

    gemm_qkv<<<dim3(24, 64), dim3(256), 0, stream>>>(Xb, WqkvT, Qb, Kb, Vt, csQ, csK);

    attn_kernel<<<dim3(512), dim3(512), 0, stream>>>(Qb, Kb, Vt, Ob);

    gemm_proj<<<dim3(8, 64), dim3(256), 0, stream>>>(Ob, WpT, (float*)d_out, bp);
}

// Round 8
// 247.304 us; speedup vs baseline: 1.1470x; 1.1470x over previous
//
#include <hip/hip_runtime.h>
#include <hip/hip_bf16.h>

#define NH 16
#define HS 64
#define CE 1024
#define BB 4
#define TT 2048

typedef __bf16 bf16;
typedef __bf16 v8bf __attribute__((ext_vector_type(8)));
typedef __bf16 v4bf __attribute__((ext_vector_type(4)));
typedef __bf16 v2bf __attribute__((ext_vector_type(2)));
typedef float v4f __attribute__((ext_vector_type(4)));
typedef float v16f __attribute__((ext_vector_type(16)));

#define GLD16(gp, lp)                                                              \
    __builtin_amdgcn_global_load_lds((const __attribute__((address_space(1))) void*)(gp), \
                                     (__attribute__((address_space(3))) void*)(lp), 16, 0, 0)

// raw-barrier discipline: sched_barrier(0) fences pin ordering around inline waits
#define FENCE() __builtin_amdgcn_sched_barrier(0)
#define BARRIER() { FENCE(); __builtin_amdgcn_s_barrier(); FENCE(); }
#define VM4()  { asm volatile("s_waitcnt vmcnt(4)" ::: "memory"); FENCE(); }
#define VM8()  { asm volatile("s_waitcnt vmcnt(8)" ::: "memory"); FENCE(); }
#define VM0()  { asm volatile("s_waitcnt vmcnt(0)" ::: "memory"); FENCE(); }

// ---------------- fused prep: cast x, cos/sin tables, 4 weight transposes ----------------
// bid [0,4096): cast x fp32->bf16 ; [4096,4352): cs tables ; [4352,5376): weight transpose
__global__ __launch_bounds__(256) void prep_kernel(const float* __restrict__ x,
                                                   const float* __restrict__ W0,
                                                   const float* __restrict__ W1,
                                                   const float* __restrict__ W2,
                                                   const float* __restrict__ W3,
                                                   bf16* __restrict__ xb,
                                                   float2* __restrict__ csQ,
                                                   float2* __restrict__ csK,
                                                   bf16* __restrict__ dqkv,
                                                   bf16* __restrict__ dp) {
    __shared__ bf16 tile[64][66];
    const int bid = blockIdx.x;
    const int tid = threadIdx.x;
    if (bid < 4096) {
        int idx = (bid * 256 + tid) * 8;
        const float4* xp = (const float4*)(x + idx);
        float4 a = xp[0], b = xp[1];
        v8bf o;
        o[0] = (bf16)a.x; o[1] = (bf16)a.y; o[2] = (bf16)a.z; o[3] = (bf16)a.w;
        o[4] = (bf16)b.x; o[5] = (bf16)b.y; o[6] = (bf16)b.z; o[7] = (bf16)b.w;
        *(v8bf*)(xb + idx) = o;
    } else if (bid < 4352) {
        int idx = (bid - 4096) * 256 + tid;  // 65536 = 2048 t x 32 i
        int t = idx >> 5, i = idx & 31;
        float inv = exp2f(-0.41524101186092034f * (float)i);  // 10000^(-i/32)
        float ang = (float)t * inv;
        float s, c;
        sincosf(ang, &s, &c);
        const float QS = 0.18033688011112042f;  // 0.125 * log2(e): softmax runs base-2
        csK[idx] = make_float2(c, s);
        csQ[idx] = make_float2(c * QS, s * QS);
    } else {
        int idx = bid - 4352;
        int z = idx >> 8, rem = idx & 255;
        const float* W = (z == 0) ? W0 : (z == 1) ? W1 : (z == 2) ? W2 : W3;
        bf16* Wt = (z < 3) ? (dqkv + (size_t)z * 1024 * CE) : dp;
        int k0 = (rem & 15) * 64;
        int n0 = (rem >> 4) * 64;
        int tx = tid & 63;
        int ty = tid >> 6;  // 0..3
        for (int s = 0; s < 16; s++) {
            int r = s * 4 + ty;
            tile[r][tx] = (bf16)W[(size_t)(k0 + r) * CE + n0 + tx];
        }
        __syncthreads();
        for (int s = 0; s < 16; s++) {
            int r = s * 4 + ty;
            Wt[(size_t)(n0 + r) * CE + k0 + tx] = tile[tx][r];
        }
    }
}

// ---------------- shared GEMM macros: BK=64, XOR-swizzled LDS, dbuf prefetch ------------
// STRUCTURAL CEILING (r2/r3): 2-phase 128^2 at K=1024 lands ~680 TF; schedule frozen.
// r5/r7: bijective XCD m-chunk swizzle + serpentine n (T1) — each XCD owns total/8
// consecutive blocks (A chunk 2MB L2-resident); inferred gain ~17us (r5->r7 differencing).
#define GSTAGE(AD, BD, kk) {                                                        \
    _Pragma("unroll") for (int p = 0; p < 4; p++)                                   \
        GLD16(Ag + (kk) + (size_t)(p * 32) * CE, (AD) + p * 2048);                  \
    _Pragma("unroll") for (int p = 0; p < 4; p++)                                   \
        GLD16(Bg + (kk) + (size_t)(p * 32) * CE, (BD) + p * 2048); }

#define GCOMPUTE(ASrc, BSrc)                                                        \
    _Pragma("unroll")                                                               \
    for (int kh = 0; kh < 2; kh++) {                                                \
        v8bf af[4], bfr[4];                                                         \
        for (int i = 0; i < 4; i++) {                                               \
            int row = wr * 64 + i * 16 + lane15;                                    \
            af[i] = *(const v8bf*)(&ASrc[row * 64 + (((kh * 4 + quad) ^ (lane15 & 7)) * 8)]); \
        }                                                                           \
        for (int j = 0; j < 4; j++) {                                               \
            int row = wc * 64 + j * 16 + lane15;                                    \
            bfr[j] = *(const v8bf*)(&BSrc[row * 64 + (((kh * 4 + quad) ^ (lane15 & 7)) * 8)]); \
        }                                                                           \
        for (int i = 0; i < 4; i++)                                                 \
            for (int j = 0; j < 4; j++)                                             \
                acc[i][j] = __builtin_amdgcn_mfma_f32_16x16x32_bf16(af[i], bfr[j], acc[i][j], 0, 0, 0); \
    }

#define GEMM_PROLOG(Abuf, Bbuf)                                                     \
    __shared__ __align__(16) bf16 As0[128 * 64];                                    \
    __shared__ __align__(16) bf16 Bs0[128 * 64];                                    \
    __shared__ __align__(16) bf16 As1[128 * 64];                                    \
    __shared__ __align__(16) bf16 Bs1[128 * 64];                                    \
    const int tid = threadIdx.x;                                                    \
    const int lane = tid & 63, wave = tid >> 6;                                     \
    const int lane15 = lane & 15, quad = lane >> 4;                                 \
    const int wr = wave >> 1, wc = wave & 1;                                        \
    const int fid = blockIdx.y * gridDim.x + blockIdx.x;                            \
    const int bchunk = (gridDim.x * gridDim.y) >> 3;                                \
    const int swzb = (fid & 7) * bchunk + (fid >> 3);                               \
    const int bmy = swzb / gridDim.x;                                               \
    const int bnx0 = swzb % gridDim.x;                                              \
    const int bnx = (bmy & 1) ? (gridDim.x - 1 - bnx0) : bnx0;                      \
    const int m0 = bmy * 128;                                                       \
    const int n0 = bnx * 128;                                                       \
    v4f acc[4][4] = {};                                                             \
    const int cm = tid >> 3;                                                        \
    const int ck = ((tid & 7) ^ (cm & 7)) * 8;                                      \
    const bf16* Ag = (Abuf) + (size_t)(m0 + cm) * CE + ck;                          \
    const bf16* Bg = (Bbuf) + (size_t)(n0 + cm) * CE + ck;                          \
    bf16* aD0 = &As0[wave * 512];                                                   \
    bf16* bD0 = &Bs0[wave * 512];                                                   \
    bf16* aD1 = &As1[wave * 512];                                                   \
    bf16* bD1 = &Bs1[wave * 512];

#define GEMM_KLOOP()                                                                \
    GSTAGE(aD0, bD0, 0);                                                            \
    for (int k0 = 0; k0 < CE; k0 += 128) {                                          \
        GSTAGE(aD1, bD1, k0 + 64);                                                  \
        VM8(); BARRIER();                                                           \
        GCOMPUTE(As0, Bs0);                                                         \
        BARRIER();                                                                  \
        GSTAGE(aD0, bD0, (k0 + 128) & 1023);                                        \
        VM8(); BARRIER();                                                           \
        GCOMPUTE(As1, Bs1);                                                         \
        BARRIER();                                                                  \
    }                                                                               \
    VM0();

// ---------------- QKV GEMM: C(8192 x 3072) = Xb * WqkvT^T, RoPE/V-transpose fused -------
__global__ __launch_bounds__(256) void gemm_qkv(const bf16* __restrict__ A,
                                                const bf16* __restrict__ Bt,
                                                bf16* __restrict__ Qb_, bf16* __restrict__ Kb_,
                                                bf16* __restrict__ Vt_,
                                                const float2* __restrict__ csQ,
                                                const float2* __restrict__ csK) {
    GEMM_PROLOG(A, Bt)
    GEMM_KLOOP()

    for (int i = 0; i < 4; i++) {
        for (int j = 0; j < 4; j++) {
            int gmb = m0 + wr * 64 + i * 16 + quad * 4;
            int gn = n0 + wc * 64 + j * 16 + lane15;
            int w = gn >> 10;           // 0=Q 1=K 2=V (block-uniform)
            int n = gn & 1023;
            int hh = n >> 6, d = n & 63;
            if (w < 2) {
                // fused RoPE, parity-row split: lane pair (d,d+1) exchanges raw acc via
                // shfl_xor(1); each lane produces BOTH rotated outputs of the pair for
                // 2 of the 4 rows (even lanes r=0,1; odd lanes r=2,3) -> 2 float2
                // cs-loads + 2 v2bf stores per tile instead of 4+4.
                bf16* out = w ? Kb_ : Qb_;
                const float2* csRow = (w ? csK : csQ) + (d >> 1);
                const int par = gn & 1;
                const int dbase = d & ~1;
                const int b = gmb >> 11, tbase = gmb & 2047;  // 4-row group never crosses b
                const float xv0 = acc[i][j][0], xv1 = acc[i][j][1];
                const float xv2 = acc[i][j][2], xv3 = acc[i][j][3];
                const float pv0 = __shfl_xor(xv0, 1), pv1 = __shfl_xor(xv1, 1);
                const float pv2 = __shfl_xor(xv2, 1), pv3 = __shfl_xor(xv3, 1);
                const float xa = par ? xv2 : xv0, pa = par ? pv2 : pv0;
                const float xb2 = par ? xv3 : xv1, pb = par ? pv3 : pv1;
                const float ua = par ? pa : xa, va = par ? xa : pa;   // (even-d, odd-d)
                const float ub = par ? pb : xb2, vb = par ? xb2 : pb;
                const int ta = tbase + (par << 1), tb = ta + 1;
                const float2 csa = csRow[ta * 32];
                const float2 csb = csRow[tb * 32];
                v2bf sa, sb;
                sa[0] = (bf16)(ua * csa.x - va * csa.y);
                sa[1] = (bf16)(ua * csa.y + va * csa.x);
                sb[0] = (bf16)(ub * csb.x - vb * csb.y);
                sb[1] = (bf16)(ub * csb.y + vb * csb.x);
                bf16* rowp = out + ((size_t)(b * NH + hh)) * TT * HS + dbase;
                *(v2bf*)(rowp + (size_t)ta * HS) = sa;
                *(v2bf*)(rowp + (size_t)tb * HS) = sb;
            } else {  // V transposed: Vt [B][H][HS][T]
                int b = gmb >> 11, t = gmb & 2047;
                v4bf pack;
                for (int r = 0; r < 4; r++) pack[r] = (bf16)acc[i][j][r];
                *(v4bf*)(&Vt_[(((size_t)(b * NH + hh)) * HS + d) * TT + t]) = pack;
            }
        }
    }
}

// ---------------- projection GEMM: out(8192 x 1024) = Ob * WpT^T + bias, fp32 ----------
__global__ __launch_bounds__(256) void gemm_proj(const bf16* __restrict__ A,
                                                 const bf16* __restrict__ Bt,
                                                 float* __restrict__ Pout,
                                                 const float* __restrict__ bias) {
    GEMM_PROLOG(A, Bt)

    // bias prefetch: acc-independent, issued before the K-loop so the epilogue's
    // stores don't sit on a fresh scattered-load latency chain after the VM0 drain.
    float bb[4];
#pragma unroll
    for (int j = 0; j < 4; j++) bb[j] = bias[n0 + wc * 64 + j * 16 + lane15];

    GEMM_KLOOP()

    for (int i = 0; i < 4; i++) {
        for (int j = 0; j < 4; j++) {
            int gmb = m0 + wr * 64 + i * 16 + quad * 4;
            int gn = n0 + wc * 64 + j * 16 + lane15;
            for (int r = 0; r < 4; r++)
                Pout[(size_t)(gmb + r) * CE + gn] = acc[i][j][r] + bb[j];
        }
    }
}

// ---------------- flash attention v8 (FROZEN): no-max base-2 softmax, dbuf prefetch -----
// 4 waves x 32 q-rows, 1024 blocks (4/CU, all resident, qb spacing {15,11,7,3} per CU =
// concurrent balance). r1/r4/r7 all proved: any trade of resident-block balance for
// per-block efficiency LOSES on this latency-bound kernel. Do not restructure.
#define ASTAGE(KD, VD, kv) {                                        \
    GLD16(kg + (size_t)(kv) * HS, (KD));                            \
    GLD16(kg + (size_t)((kv) + 32) * HS, (KD) + 2048);              \
    GLD16(vg + (kv), (VD));                                         \
    GLD16(vg + (kv) + 32 * TT, (VD) + 2048); }

#define ACOMPUTE(KS, VS, KVB)                                                       \
    _Pragma("unroll")                                                               \
    for (int sub = 0; sub < 2; sub++) {                                             \
        const int kvs = (KVB) + sub * 32;                                           \
        if (kvs > q0) break;                                                        \
        const bool diag = (kvs == q0);                                              \
        v16f s = {};                                                                \
        __builtin_amdgcn_s_setprio(1);                                              \
        for (int m = 0; m < 4; m++) {                                               \
            v8bf afr = *(const v8bf*)(&KS[(sub * 32 + lane31) * 64 +                \
                                          (((m << 1) | h) ^ (lane31 & 7)) * 8]);    \
            s = __builtin_amdgcn_mfma_f32_32x32x16_bf16(afr, qf[m], s, 0, 0, 0);    \
        }                                                                           \
        __builtin_amdgcn_s_setprio(0);                                              \
        float p[16];                                                                \
        if (diag) {                                                                 \
            for (int r = 0; r < 16; r++) {                                          \
                int kvr = (r & 3) + 8 * (r >> 2) + 4 * h;                           \
                p[r] = exp2f((kvr <= lane31) ? s[r] : -3.0e38f);                    \
            }                                                                       \
        } else {                                                                    \
            for (int r = 0; r < 16; r++) p[r] = exp2f(s[r]);                        \
        }                                                                           \
        float a8[8];                                                                \
        for (int r = 0; r < 8; r++) a8[r] = p[r] + p[r + 8];                        \
        l_i += ((a8[0] + a8[1]) + (a8[2] + a8[3])) + ((a8[4] + a8[5]) + (a8[6] + a8[7])); \
        union { v4bf v; unsigned long long u; } ch[4];                              \
        for (int g = 0; g < 4; g++)                                                 \
            for (int rr = 0; rr < 4; rr++)                                          \
                ch[g].v[rr] = (bf16)p[g * 4 + rr];                                  \
        __builtin_amdgcn_s_setprio(1);                                              \
        for (int t2 = 0; t2 < 2; t2++) {                                            \
            unsigned long long mine0 = ch[2 * t2].u, mine1 = ch[2 * t2 + 1].u;      \
            unsigned long long send = h ? mine0 : mine1;                            \
            unsigned long long recv = __shfl_xor(send, 32);                         \
            union { v8bf v; unsigned long long u[2]; } bfr2;                        \
            bfr2.u[0] = h ? recv : mine0;                                           \
            bfr2.u[1] = h ? mine1 : recv;                                           \
            int cidx = (((sub << 2) + (t2 << 1) + h) ^ (lane31 & 7)) * 8;           \
            v8bf va0 = *(const v8bf*)(&VS[lane31 * 64 + cidx]);                     \
            o0 = __builtin_amdgcn_mfma_f32_32x32x16_bf16(va0, bfr2.v, o0, 0, 0, 0); \
            v8bf va1 = *(const v8bf*)(&VS[(32 + lane31) * 64 + cidx]);              \
            o1 = __builtin_amdgcn_mfma_f32_32x32x16_bf16(va1, bfr2.v, o1, 0, 0, 0); \
        }                                                                           \
        __builtin_amdgcn_s_setprio(0);                                              \
    }

__global__ __launch_bounds__(256, 4) void attn_kernel(const bf16* __restrict__ Qb,
                                                      const bf16* __restrict__ Kb,
                                                      const bf16* __restrict__ Vt,
                                                      bf16* __restrict__ Ob) {
    __shared__ __align__(16) bf16 Ks0[64 * 64];  // [kv][d], chunk-swizzled
    __shared__ __align__(16) bf16 Vs0[64 * 64];  // [d][kv], chunk-swizzled
    __shared__ __align__(16) bf16 Ks1[64 * 64];
    __shared__ __align__(16) bf16 Vs1[64 * 64];
    const int tid = threadIdx.x, lane = tid & 63, wave = tid >> 6;
    const int lane31 = lane & 31, h = lane >> 5;
    const int bh = blockIdx.x & 63;
    const int qb = 15 - (int)(blockIdx.x >> 6);  // heavy q-tiles first
    const int q0 = qb * 128 + wave * 32;
    const bf16* Qp = Qb + (size_t)bh * TT * HS;
    const bf16* Kp = Kb + (size_t)bh * TT * HS;
    const bf16* Vp = Vt + (size_t)bh * HS * TT;

    // Q B-fragments: B[n=q=lane31][k=d in 16m+8h+j]
    v8bf qf[4];
    for (int m = 0; m < 4; m++)
        qf[m] = *(const v8bf*)(Qp + (size_t)(q0 + lane31) * HS + m * 16 + h * 8);

    v16f o0 = {}, o1 = {};   // O^T rows d=0..31 / 32..63, col q=lane31 (unnormalized)
    float l_i = 0.f;         // per-lane half-row sum; cross-lane combine at end

    // staging source (XOR-swizzled chunk); dest = tid*16B per 4KB quarter
    const int kr = tid >> 3, kc = tid & 7;
    const bf16* kg = Kp + kr * HS + ((kc ^ (kr & 7)) * 8);
    const bf16* vg = Vp + (size_t)kr * TT + ((kc ^ (kr & 7)) * 8);
    bf16* ksD0 = &Ks0[wave * 512];
    bf16* vsD0 = &Vs0[wave * 512];
    bf16* ksD1 = &Ks1[wave * 512];
    bf16* vsD1 = &Vs1[wave * 512];

    const int kv_max = qb * 128 + 96;
    ASTAGE(ksD0, vsD0, 0);
    for (int kv0 = 0; kv0 <= kv_max; kv0 += 128) {
        ASTAGE(ksD1, vsD1, kv0 + 64);              // prefetch tile t+1 (<= 1984, in range)
        VM4(); BARRIER();                          // tile t landed (4 newer in flight)
        ACOMPUTE(Ks0, Vs0, kv0);
        BARRIER();                                 // all readers of buf0 done
        ASTAGE(ksD0, vsD0, (kv0 + 128) & 2047);    // prefetch t+2 (wraps to dummy at end)
        VM4(); BARRIER();                          // tile t+1 landed
        ACOMPUTE(Ks1, Vs1, kv0 + 64);
        BARRIER();
    }
    VM0();  // drain dangling dummy prefetches

    const int b = bh >> 4, hh = bh & 15;
    const int q = q0 + lane31;
    float lt = l_i + __shfl_xor(l_i, 32);  // combine the two half-row sums once
    float invl = 1.f / lt;
    bf16* outRow = Ob + ((size_t)(b * TT + q)) * CE + hh * HS;
    for (int g = 0; g < 4; g++) {
        v4bf w0, w1;
        for (int rr = 0; rr < 4; rr++) {
            w0[rr] = (bf16)(o0[g * 4 + rr] * invl);
            w1[rr] = (bf16)(o1[g * 4 + rr] * invl);
        }
        *(v4bf*)(outRow + g * 8 + h * 4) = w0;
        *(v4bf*)(outRow + 32 + g * 8 + h * 4) = w1;
    }
}

extern "C" void kernel_launch(void* const* d_in, const int* in_sizes, int n_in,
                              void* d_out, int out_size, void* d_ws, size_t ws_size,
                              hipStream_t stream) {
    const float* x  = (const float*)d_in[0];
    const float* Wq = (const float*)d_in[1];
    const float* Wk = (const float*)d_in[2];
    const float* Wv = (const float*)d_in[3];
    const float* Wp = (const float*)d_in[4];
    const float* bp = (const float*)d_in[5];
    char* ws = (char*)d_ws;
    const size_t MB = 1024 * 1024;
    bf16* Xb    = (bf16*)(ws);                // 16MB
    bf16* WqkvT = (bf16*)(ws + 16 * MB);      // 6MB: 3072 x 1024 (Q,K,V stacked)
    bf16* WpT   = (bf16*)(ws + 22 * MB);      // 2MB
    bf16* Qb    = (bf16*)(ws + 24 * MB);      // 16MB
    bf16* Kb    = (bf16*)(ws + 40 * MB);      // 16MB
    bf16* Vt    = (bf16*)(ws + 56 * MB);      // 16MB
    bf16* Ob    = (bf16*)(ws + 72 * MB);      // 16MB (attn output)
    // cs tables live in the Ob region: consumed by the QKV GEMM, which completes
    // before attn writes Ob (single stream). 1MB total.
    float2* csQ = (float2*)(ws + 72 * MB);
    float2* csK = (float2*)(ws + 72 * MB + 512 * 1024);

    prep_kernel<<<dim3(5376), dim3(256), 0, stream>>>(x, Wq, Wk, Wv, Wp, Xb, csQ, csK,
                                                      WqkvT, WpT);

    gemm_qkv<<<dim3(24, 64), dim3(256), 0, stream>>>(Xb, WqkvT, Qb, Kb, Vt, csQ, csK);

    attn_kernel<<<dim3(1024), dim3(256), 0, stream>>>(Qb, Kb, Vt, Ob);

    gemm_proj<<<dim3(8, 64), dim3(256), 0, stream>>>(Ob, WpT, (float*)d_out, bp);
}